// Round 1
// baseline (38484.521 us; speedup 1.0000x reference)
//
#include <hip/hip_runtime.h>
#include <cstdint>
#include <cstddef>

#define FLAG_BIAS 1
#define FLAG_GELU 2
#define FLAG_ACC  4

static constexpr int Dm   = 768;
static constexpr int Ssz  = 500;
static constexpr int HIDc = 1536;

__device__ __forceinline__ float gelu_f(float v) {
  return 0.5f * v * (1.0f + erff(v * 0.7071067811865475f));
}

// ---------------- conv (patch embed) + pos embed -> tok ----------------
// tok[b,s,d] = sum_{f<64,t<4} x[b,0,f,4s+t]*cw[d,0,f,t] + cb[d] + pe[s,d]
__global__ __launch_bounds__(256) void conv_kernel(const float* __restrict__ x,
                                                   const float* __restrict__ cw,
                                                   const float* __restrict__ cb,
                                                   const float* __restrict__ pe,
                                                   float* __restrict__ tok) {
  __shared__ float ps[16][256];
  int b = blockIdx.y;
  int s0 = blockIdx.x * 16;
  int tid = threadIdx.x;
  for (int idxv = tid; idxv < 16 * 256; idxv += 256) {
    int sl = idxv >> 8, k = idxv & 255;
    int s = s0 + sl;
    int f = k >> 2, t = k & 3;
    ps[sl][k] = (s < Ssz) ? x[b * 128000 + f * 2000 + 4 * s + t] : 0.f;
  }
  __syncthreads();
  for (int d = tid; d < Dm; d += 256) {
    float acc[16];
#pragma unroll
    for (int sl = 0; sl < 16; ++sl) acc[sl] = 0.f;
    for (int k = 0; k < 256; ++k) {
      float w = cw[d * 256 + k];
#pragma unroll
      for (int sl = 0; sl < 16; ++sl) acc[sl] += w * ps[sl][k];
    }
    float bb = cb[d];
    for (int sl = 0; sl < 16; ++sl) {
      int s = s0 + sl;
      if (s < Ssz)
        tok[((size_t)b * Ssz + s) * Dm + d] = acc[sl] + bb + pe[s * Dm + d];
    }
  }
}

// ---------------- layernorm over D=768, block=256, one row/block ----------------
__device__ __forceinline__ float block_sum_256(float v, float* red) {
#pragma unroll
  for (int o = 32; o > 0; o >>= 1) v += __shfl_down(v, o);
  int lane = threadIdx.x & 63, w = threadIdx.x >> 6;
  if (lane == 0) red[w] = v;
  __syncthreads();
  return red[0] + red[1] + red[2] + red[3];
}

__global__ __launch_bounds__(256) void ln_kernel(const float* __restrict__ in,
                                                 const float* __restrict__ sc,
                                                 const float* __restrict__ bi,
                                                 float* __restrict__ out) {
  __shared__ float redA[4], redB[4];
  int r = blockIdx.x;
  const float* xr = in + (size_t)r * Dm;
  int tid = threadIdx.x;
  float v[3];
  float sum = 0.f;
#pragma unroll
  for (int i = 0; i < 3; ++i) { v[i] = xr[tid + i * 256]; sum += v[i]; }
  float tot = block_sum_256(sum, redA);
  float mu = tot * (1.f / 768.f);
  float var = 0.f;
#pragma unroll
  for (int i = 0; i < 3; ++i) { float d = v[i] - mu; var += d * d; }
  float vt = block_sum_256(var, redB) * (1.f / 768.f);
  float rs = rsqrtf(vt + 1e-5f);
  float* orow = out + (size_t)r * Dm;
#pragma unroll
  for (int i = 0; i < 3; ++i) {
    int e = tid + i * 256;
    orow[e] = (v[i] - mu) * rs * sc[e] + bi[e];
  }
}

// ---------------- generic fp32 tiled GEMM: C[M,N] = A[M,K](lda=K) * B[K,N](ldb) ----------------
__device__ __forceinline__ void gemm_tile_body(const float* __restrict__ A,
                                               const float* __restrict__ Bm,
                                               int M, int N, int Kd, int ldb,
                                               int row0, int col0,
                                               float (&As)[16][68], float (&Bs)[16][68],
                                               float (&acc)[4][4]) {
  int tid = threadIdx.x;
  int aRow = tid >> 2, aCol = (tid & 3) * 4;
  int bRow = tid >> 4, bCol = (tid & 15) * 4;
  int tx = tid & 15, ty = tid >> 4;
  int gr = row0 + aRow;
  const float* Arow = (gr < M) ? (A + (size_t)gr * Kd) : nullptr;
  for (int k0 = 0; k0 < Kd; k0 += 16) {
#pragma unroll
    for (int j = 0; j < 4; ++j)
      As[aCol + j][aRow] = Arow ? Arow[k0 + aCol + j] : 0.f;
    const float* Brow = Bm + (size_t)(k0 + bRow) * ldb + col0;
#pragma unroll
    for (int j = 0; j < 4; ++j) {
      int c = bCol + j;
      Bs[bRow][c] = (col0 + c < N) ? Brow[c] : 0.f;
    }
    __syncthreads();
#pragma unroll
    for (int kk = 0; kk < 16; ++kk) {
      const float4 av = *reinterpret_cast<const float4*>(&As[kk][ty * 4]);
      const float4 bv = *reinterpret_cast<const float4*>(&Bs[kk][tx * 4]);
      float a[4] = {av.x, av.y, av.z, av.w};
      float b[4] = {bv.x, bv.y, bv.z, bv.w};
#pragma unroll
      for (int i = 0; i < 4; ++i)
#pragma unroll
        for (int j = 0; j < 4; ++j)
          acc[i][j] += a[i] * b[j];
    }
    __syncthreads();
  }
}

__global__ __launch_bounds__(256) void gemm_kernel(const float* __restrict__ A,
                                                   const float* __restrict__ Bm,
                                                   const float* __restrict__ bias,
                                                   float* __restrict__ C,
                                                   int M, int N, int Kd, int ldb, int ldc,
                                                   int flags) {
  __shared__ float As[16][68], Bs[16][68];
  float acc[4][4] = {{0.f}};
  int row0 = blockIdx.y * 64, col0 = blockIdx.x * 64;
  gemm_tile_body(A, Bm, M, N, Kd, ldb, row0, col0, As, Bs, acc);
  int tx = threadIdx.x & 15, ty = threadIdx.x >> 4;
#pragma unroll
  for (int i = 0; i < 4; ++i) {
    int r = row0 + ty * 4 + i;
    if (r >= M) continue;
#pragma unroll
    for (int j = 0; j < 4; ++j) {
      int c = col0 + tx * 4 + j;
      if (c >= N) continue;
      float v = acc[i][j];
      if (flags & FLAG_BIAS) v += bias[c];
      if (flags & FLAG_GELU) v = gelu_f(v);
      float* p = C + (size_t)r * ldc + c;
      if (flags & FLAG_ACC) *p += v; else *p = v;
    }
  }
}

// ---------------- MoE expert GEMMs (per-batch expert indirection) ----------------
__global__ __launch_bounds__(256) void moe1_kernel(const float* __restrict__ xn,
                                                   const float* __restrict__ ew1,
                                                   const float* __restrict__ eb1,
                                                   const int* __restrict__ idx,
                                                   float* __restrict__ hmid, int ksel) {
  int b = blockIdx.z;
  int e = idx[b * 4 + ksel];
  const float* A = xn + (size_t)b * Ssz * Dm;
  const float* W = ew1 + (size_t)e * Dm * HIDc;
  const float* bias = eb1 + (size_t)e * HIDc;
  __shared__ float As[16][68], Bs[16][68];
  float acc[4][4] = {{0.f}};
  int row0 = blockIdx.y * 64, col0 = blockIdx.x * 64;
  gemm_tile_body(A, W, Ssz, HIDc, Dm, HIDc, row0, col0, As, Bs, acc);
  int tx = threadIdx.x & 15, ty = threadIdx.x >> 4;
  float* C = hmid + (size_t)b * Ssz * HIDc;
#pragma unroll
  for (int i = 0; i < 4; ++i) {
    int r = row0 + ty * 4 + i;
    if (r >= Ssz) continue;
#pragma unroll
    for (int j = 0; j < 4; ++j) {
      int c = col0 + tx * 4 + j;
      C[(size_t)r * HIDc + c] = gelu_f(acc[i][j] + bias[c]);
    }
  }
}

__global__ __launch_bounds__(256) void moe2_kernel(const float* __restrict__ hmid,
                                                   const float* __restrict__ ew2,
                                                   const float* __restrict__ eb2,
                                                   const int* __restrict__ idx,
                                                   const float* __restrict__ wgt,
                                                   float* __restrict__ y, int ksel) {
  int b = blockIdx.z;
  int e = idx[b * 4 + ksel];
  float w = wgt[b * 4 + ksel];
  const float* A = hmid + (size_t)b * Ssz * HIDc;
  const float* W = ew2 + (size_t)e * HIDc * Dm;
  const float* bias = eb2 + (size_t)e * Dm;
  __shared__ float As[16][68], Bs[16][68];
  float acc[4][4] = {{0.f}};
  int row0 = blockIdx.y * 64, col0 = blockIdx.x * 64;
  gemm_tile_body(A, W, Ssz, Dm, HIDc, Dm, row0, col0, As, Bs, acc);
  int tx = threadIdx.x & 15, ty = threadIdx.x >> 4;
  float* C = y + (size_t)b * Ssz * Dm;
#pragma unroll
  for (int i = 0; i < 4; ++i) {
    int r = row0 + ty * 4 + i;
    if (r >= Ssz) continue;
#pragma unroll
    for (int j = 0; j < 4; ++j) {
      int c = col0 + tx * 4 + j;
      C[(size_t)r * Dm + c] += w * (acc[i][j] + bias[c]);
    }
  }
}

// ---------------- attention: 16 q / block, K/V tiles of 64 staged in LDS ----------------
// qkv layout: qkv[(b*S+s)*2304 + part*768 + h*64 + dh]
__global__ __launch_bounds__(256) void attn_kernel(const float* __restrict__ qkv,
                                                   float* __restrict__ out) {
  __shared__ float q_s[16][65];
  __shared__ float kv_s[64][65];
  __shared__ float p_s[16][512];
  int b = blockIdx.z, h = blockIdx.y, qt = blockIdx.x;
  int tid = threadIdx.x, lane = tid & 63, wv = tid >> 6;
  int q0 = qt * 16;
  for (int ql = wv; ql < 16; ql += 4) {
    int s = q0 + ql;
    q_s[ql][lane] = (s < Ssz) ? qkv[((size_t)b * Ssz + s) * 2304 + h * 64 + lane] : 0.f;
  }
  __syncthreads();
  // phase 1: scores -> p_s (pre-softmax, scaled)
  for (int kb = 0; kb < 8; ++kb) {
    int k0 = kb * 64;
    for (int i = wv; i < 64; i += 4) {
      int s = k0 + i;
      kv_s[i][lane] = (s < Ssz) ? qkv[((size_t)b * Ssz + s) * 2304 + 768 + h * 64 + lane] : 0.f;
    }
    __syncthreads();
#pragma unroll
    for (int j = 0; j < 4; ++j) {
      int ql = wv * 4 + j;
      float s = 0.f;
#pragma unroll 16
      for (int d = 0; d < 64; ++d) s += q_s[ql][d] * kv_s[lane][d];
      p_s[ql][k0 + lane] = s * 0.125f;
    }
    __syncthreads();
  }
  // phase 2: softmax per q row (each wave owns 4 rows)
  float rcp[4];
#pragma unroll
  for (int j = 0; j < 4; ++j) {
    int ql = wv * 4 + j;
    float m = -1e30f;
#pragma unroll
    for (int kb = 0; kb < 8; ++kb) {
      int k = kb * 64 + lane;
      if (k < Ssz) m = fmaxf(m, p_s[ql][k]);
    }
#pragma unroll
    for (int o = 32; o > 0; o >>= 1) m = fmaxf(m, __shfl_xor(m, o));
    float sum = 0.f;
#pragma unroll
    for (int kb = 0; kb < 8; ++kb) {
      int k = kb * 64 + lane;
      float p = (k < Ssz) ? expf(p_s[ql][k] - m) : 0.f;
      p_s[ql][k] = p;
      sum += p;
    }
#pragma unroll
    for (int o = 32; o > 0; o >>= 1) sum += __shfl_xor(sum, o);
    rcp[j] = 1.f / sum;
  }
  __syncthreads();
  // phase 3: P @ V
  float o4[4] = {0.f, 0.f, 0.f, 0.f};
  for (int kb = 0; kb < 8; ++kb) {
    int k0 = kb * 64;
    for (int i = wv; i < 64; i += 4) {
      int s = k0 + i;
      kv_s[i][lane] = (s < Ssz) ? qkv[((size_t)b * Ssz + s) * 2304 + 1536 + h * 64 + lane] : 0.f;
    }
    __syncthreads();
#pragma unroll 8
    for (int i = 0; i < 64; ++i) {
      float vv = kv_s[i][lane];
      int k = k0 + i;
#pragma unroll
      for (int j = 0; j < 4; ++j) o4[j] += p_s[wv * 4 + j][k] * vv;
    }
    __syncthreads();
  }
#pragma unroll
  for (int j = 0; j < 4; ++j) {
    int s = q0 + wv * 4 + j;
    if (s < Ssz) out[((size_t)b * Ssz + s) * Dm + h * 64 + lane] = o4[j] * rcp[j];
  }
}

// ---------------- seq mean over S ----------------
__global__ __launch_bounds__(256) void seqmean_kernel(const float* __restrict__ xn,
                                                      float* __restrict__ seq) {
  int b = blockIdx.y;
  int d = blockIdx.x * 256 + threadIdx.x;
  float s = 0.f;
  for (int t = 0; t < Ssz; ++t) s += xn[((size_t)b * Ssz + t) * Dm + d];
  seq[b * Dm + d] = s * (1.f / 500.f);
}

// ---------------- gate: logits -> softmax -> top4 -> softmax weights ----------------
__global__ __launch_bounds__(64) void gate_kernel(const float* __restrict__ g1,
                                                  const float* __restrict__ w2,
                                                  const float* __restrict__ b2,
                                                  int* __restrict__ idx_out,
                                                  float* __restrict__ w_out) {
  int b = blockIdx.x, lane = threadIdx.x;
  __shared__ float g1s[768];
  __shared__ float lg[16];
  for (int j = lane; j < 768; j += 64) g1s[j] = g1[b * 768 + j];
  __syncthreads();
  if (lane < 14) {
    float acc = b2[lane];
    for (int j = 0; j < 768; ++j) acc += g1s[j] * w2[(size_t)j * 14 + lane];
    lg[lane] = acc;
  }
  __syncthreads();
  if (lane == 0) {
    float m = lg[0];
    for (int e = 1; e < 14; ++e) m = fmaxf(m, lg[e]);
    float p[14]; float sm = 0.f;
    for (int e = 0; e < 14; ++e) { p[e] = expf(lg[e] - m); sm += p[e]; }
    for (int e = 0; e < 14; ++e) p[e] /= sm;
    bool used[14] = {};
    float tp[4]; int ti[4];
    for (int k = 0; k < 4; ++k) {
      float bv = -1.f; int bi = 0;
      for (int e = 0; e < 14; ++e)
        if (!used[e] && p[e] > bv) { bv = p[e]; bi = e; }
      used[bi] = true; tp[k] = bv; ti[k] = bi;
    }
    float s2 = 0.f; float wk[4];
    for (int k = 0; k < 4; ++k) { wk[k] = expf(tp[k] - tp[0]); s2 += wk[k]; }
    for (int k = 0; k < 4; ++k) { idx_out[b * 4 + k] = ti[k]; w_out[b * 4 + k] = wk[k] / s2; }
  }
}

// ---------------- elementwise add ----------------
__global__ __launch_bounds__(256) void add_kernel(float* __restrict__ a,
                                                  const float* __restrict__ bsrc, int n) {
  int i = blockIdx.x * 256 + threadIdx.x;
  if (i < n) a[i] += bsrc[i];
}

extern "C" void kernel_launch(void* const* d_in, const int* in_sizes, int n_in,
                              void* d_out, int out_size, void* d_ws, size_t ws_size,
                              hipStream_t stream) {
  (void)in_sizes; (void)n_in; (void)out_size; (void)ws_size;
  const float* x       = (const float*)d_in[0];
  const float* conv_w  = (const float*)d_in[1];
  const float* conv_b  = (const float*)d_in[2];
  const float* pos     = (const float*)d_in[3];
  const float* ln1_s   = (const float*)d_in[4];
  const float* ln1_b   = (const float*)d_in[5];
  const float* w_qkv   = (const float*)d_in[6];
  const float* w_proj  = (const float*)d_in[7];
  const float* b_proj  = (const float*)d_in[8];
  const float* ln2_s   = (const float*)d_in[9];
  const float* ln2_b   = (const float*)d_in[10];
  const float* gate_w1 = (const float*)d_in[11];
  const float* gate_b1 = (const float*)d_in[12];
  const float* gate_w2 = (const float*)d_in[13];
  const float* gate_b2 = (const float*)d_in[14];
  const float* exp_w1  = (const float*)d_in[15];
  const float* exp_b1  = (const float*)d_in[16];
  const float* exp_w2  = (const float*)d_in[17];
  const float* exp_b2  = (const float*)d_in[18];
  const float* sh_w1   = (const float*)d_in[19];
  const float* sh_b1   = (const float*)d_in[20];
  const float* sh_w2   = (const float*)d_in[21];
  const float* sh_b2   = (const float*)d_in[22];
  const float* lnf_s   = (const float*)d_in[23];
  const float* lnf_b   = (const float*)d_in[24];

  float* ws = (float*)d_ws;
  size_t off = 0;
  auto alloc = [&](size_t n) { float* p = ws + off; off += (n + 63) & ~(size_t)63; return p; };
  float* tok  = alloc(12288000);   // (B*S, D)
  float* xn   = alloc(12288000);   // ln output / attn output (reused)
  float* y    = alloc(12288000);   // ffn+moe accumulator
  float* regA = alloc(36864000);   // qkv (16000x2304) / sh-hidden chunk / moe hidden
  float* seq  = alloc(32 * 768);
  float* g1   = alloc(32 * 768);
  float* wgt  = alloc(128);
  int*   idx  = (int*)alloc(128);

  const int M = 16000;  // B*S
  conv_kernel<<<dim3(32, 32), 256, 0, stream>>>(x, conv_w, conv_b, pos, tok);
  for (int l = 0; l < 4; ++l) {
    ln_kernel<<<M, 256, 0, stream>>>(tok, ln1_s + l * 768, ln1_b + l * 768, xn);
    gemm_kernel<<<dim3(36, 250), 256, 0, stream>>>(xn, w_qkv + (size_t)l * 768 * 2304, nullptr,
                                                   regA, M, 2304, 768, 2304, 2304, 0);
    attn_kernel<<<dim3(32, 12, 32), 256, 0, stream>>>(regA, xn);
    gemm_kernel<<<dim3(12, 250), 256, 0, stream>>>(xn, w_proj + (size_t)l * 768 * 768,
                                                   b_proj + l * 768, tok,
                                                   M, 768, 768, 768, 768, FLAG_BIAS | FLAG_ACC);
    ln_kernel<<<M, 256, 0, stream>>>(tok, ln2_s + l * 768, ln2_b + l * 768, xn);
    seqmean_kernel<<<dim3(3, 32), 256, 0, stream>>>(xn, seq);
    gemm_kernel<<<dim3(12, 1), 256, 0, stream>>>(seq, gate_w1 + (size_t)l * 768 * 768,
                                                 gate_b1 + l * 768, g1,
                                                 32, 768, 768, 768, 768, FLAG_BIAS | FLAG_GELU);
    gate_kernel<<<32, 64, 0, stream>>>(g1, gate_w2 + (size_t)l * 768 * 14, gate_b2 + l * 14,
                                       idx, wgt);
    // shared FFN in two 1536-wide chunks (regA holds the hidden chunk)
    for (int c = 0; c < 2; ++c) {
      int c0 = c * 1536;
      gemm_kernel<<<dim3(24, 250), 256, 0, stream>>>(xn, sh_w1 + (size_t)l * 768 * 3072 + c0,
                                                     sh_b1 + l * 3072 + c0, regA,
                                                     M, 1536, 768, 3072, 1536,
                                                     FLAG_BIAS | FLAG_GELU);
      gemm_kernel<<<dim3(12, 250), 256, 0, stream>>>(regA,
                                                     sh_w2 + (size_t)l * 3072 * 768 + (size_t)c0 * 768,
                                                     (c == 0) ? (sh_b2 + l * 768) : nullptr, y,
                                                     M, 768, 1536, 768, 768,
                                                     (c == 0) ? FLAG_BIAS : FLAG_ACC);
    }
    for (int k = 0; k < 4; ++k) {
      moe1_kernel<<<dim3(24, 8, 32), 256, 0, stream>>>(xn, exp_w1 + (size_t)l * 14 * 768 * 1536,
                                                       exp_b1 + (size_t)l * 14 * 1536, idx, regA, k);
      moe2_kernel<<<dim3(12, 8, 32), 256, 0, stream>>>(regA, exp_w2 + (size_t)l * 14 * 1536 * 768,
                                                       exp_b2 + (size_t)l * 14 * 768, idx, wgt, y, k);
    }
    add_kernel<<<48000, 256, 0, stream>>>(tok, y, 12288000);
  }
  ln_kernel<<<M, 256, 0, stream>>>(tok, lnf_s, lnf_b, (float*)d_out);
}